// Round 9
// baseline (451.516 us; speedup 1.0000x reference)
//
#include <hip/hip_runtime.h>
#include <hip/hip_bf16.h>

typedef __hip_bfloat16 bf16;

#define BB 16
#define LL 512
#define DD 512
#define NHH 8
#define HDD 64
#define TT 17
#define MM (BB*LL)   // 8192 rows
#define RCH 8        // rel-attn key chunks
#define RCK 65       // keys per chunk (8*65=520 >= 513)

typedef __attribute__((ext_vector_type(8))) short bfrag;   // 8 bf16
typedef __attribute__((ext_vector_type(4))) float ffrag;   // 4 fp32
typedef __attribute__((ext_vector_type(8))) unsigned short us8;

static __device__ __forceinline__ void gld16(const void* g, void* l){
  __builtin_amdgcn_global_load_lds((const __attribute__((address_space(1))) void*)g,
                                   (__attribute__((address_space(3))) void*)l, 16, 0, 0);
}
static __device__ __forceinline__ float us2f(unsigned short u){
  unsigned int v = ((unsigned int)u) << 16;
  float f; __builtin_memcpy(&f, &v, 4); return f;
}

// ---------------- embedding gather -> bf16 ----------------
__global__ void embed_kernel(const int* __restrict__ tokens, const float* __restrict__ emb,
                             bf16* __restrict__ ebf, int total){
  int i = blockIdx.x*blockDim.x + threadIdx.x;
  if (i < total) {
    int t = tokens[i >> 9];
    int d = i & 511;
    ebf[i] = __float2bfloat16(emb[(size_t)t*DD + d]);
  }
}

// ---------------- mean stage 1: partial sums over 32-row chunks ----------------
__global__ void mean1(const bf16* __restrict__ e, float* __restrict__ part){
  int blk = blockIdx.x;            // 256 = 16 b x 16 chunks
  int b = blk >> 4, lc = blk & 15;
  int t = threadIdx.x;
  const bf16* p = e + ((size_t)b*LL + lc*32)*DD;
  for (int d = t; d < DD; d += 256){
    float acc = 0.f;
    #pragma unroll 4
    for (int l = 0; l < 32; l++) acc += __bfloat162float(p[(size_t)l*DD + d]);
    part[(size_t)blk*DD + d] = acc;
  }
}
// ---------------- mean stage 2 ----------------
__global__ void mean2(const float* __restrict__ part, float* __restrict__ s){
  int i = blockIdx.x*256 + threadIdx.x;   // 8192
  int b = i >> 9, d = i & 511;
  float acc = 0.f;
  #pragma unroll
  for (int c = 0; c < 16; c++) acc += part[(size_t)(b*16 + c)*DD + d];
  s[i] = acc * (1.0f/LL);
}

// ---------------- 6x W[512][512] fp32 -> Wt bf16 (transposed), one launch ----------------
__global__ void prep_w(const float* __restrict__ i0, const float* __restrict__ i1,
                       const float* __restrict__ i2, const float* __restrict__ i3,
                       const float* __restrict__ i4, const float* __restrict__ i5,
                       bf16* __restrict__ o0, bf16* __restrict__ o1,
                       bf16* __restrict__ o2, bf16* __restrict__ o3,
                       bf16* __restrict__ o4, bf16* __restrict__ o5){
  __shared__ float tile[32][33];
  int z = blockIdx.z;
  const float* in = (z==0)?i0:(z==1)?i1:(z==2)?i2:(z==3)?i3:(z==4)?i4:i5;
  bf16* out       = (z==0)?o0:(z==1)?o1:(z==2)?o2:(z==3)?o3:(z==4)?o4:o5;
  int tx = threadIdx.x, ty = threadIdx.y;       // 32 x 8
  int bx = blockIdx.x*32, by = blockIdx.y*32;
  #pragma unroll
  for (int j = 0; j < 32; j += 8)
    tile[ty + j][tx] = in[(size_t)(by + ty + j)*DD + bx + tx];
  __syncthreads();
  #pragma unroll
  for (int j = 0; j < 32; j += 8)
    out[(size_t)(bx + ty + j)*DD + by + tx] = __float2bfloat16(tile[tx][ty + j]);
}

// ---------------- ofc_w[512][17] -> WtLog[128][512] bf16 (transposed, zero-padded) ----------------
__global__ void pad_logw(const float* __restrict__ w, bf16* __restrict__ out){
  int i = blockIdx.x*blockDim.x + threadIdx.x;   // 128*512 total
  int row = i >> 9, k = i & 511;
  out[i] = __float2bfloat16(row < TT ? w[(size_t)k*TT + row] : 0.f);
}

// ---------------- MFMA GEMM, bf16 output, split destination ----------------
// cols < split -> D0 (ld0); cols >= split -> D1 at col-split (ld1)
__global__ __launch_bounds__(256)
void gemm_mfma_bf(const bf16* __restrict__ A, const bf16* __restrict__ Wt,
                  const float* __restrict__ b0, const float* __restrict__ b1,
                  const float* __restrict__ b2,
                  bf16* __restrict__ D0, int ld0,
                  bf16* __restrict__ D1, int ld1, int split){
  const int K = 512;
  __shared__ bf16 As[128*32];
  __shared__ bf16 Bs[128*32];
  int t = threadIdx.x;
  int wave = t >> 6, lane = t & 63;
  int bm = blockIdx.y * 128, bn = blockIdx.x * 128;
  int wm = (wave & 1) * 64, wn = (wave >> 1) * 64;
  ffrag acc[4][4];
  #pragma unroll
  for (int i = 0; i < 4; i++)
    #pragma unroll
    for (int j = 0; j < 4; j++) acc[i][j] = (ffrag){0.f,0.f,0.f,0.f};

  int srow = t >> 2;
  int scol = (t & 3) * 8;
  const bf16* gA = A  + (size_t)(bm + srow)*K + scol;
  const bf16* gB = Wt + (size_t)(bn + srow)*K + scol;
  char* lA = (char*)As + 16*t;
  char* lB = (char*)Bs + 16*t;
  int q = lane >> 4, r = lane & 15;

  for (int k0 = 0; k0 < K; k0 += 32){
    gld16(gA + k0,          lA);
    gld16(gA + 64*K + k0,   lA + 4096);
    gld16(gB + k0,          lB);
    gld16(gB + 64*K + k0,   lB + 4096);
    __syncthreads();
    bfrag af[4], bfv[4];
    #pragma unroll
    for (int i = 0; i < 4; i++){
      af[i]  = *(const bfrag*)(As + (wm + i*16 + r)*32 + q*8);
      bfv[i] = *(const bfrag*)(Bs + (wn + i*16 + r)*32 + q*8);
    }
    #pragma unroll
    for (int i = 0; i < 4; i++)
      #pragma unroll
      for (int j = 0; j < 4; j++)
        acc[i][j] = __builtin_amdgcn_mfma_f32_16x16x32_bf16(af[i], bfv[j], acc[i][j], 0, 0, 0);
    __syncthreads();
  }
  #pragma unroll
  for (int i = 0; i < 4; i++){
    #pragma unroll
    for (int j = 0; j < 4; j++){
      int row = bm + wm + i*16 + q*4;
      int col = bn + wn + j*16 + r;
      const float* bp = (col < 512) ? b0 : (col < 1024) ? b1 : b2;
      float bias = bp[col & 511];
      bf16* D; int ld;
      if (col < split){ D = D0 + (size_t)row*ld0 + col;        ld = ld0; }
      else            { D = D1 + (size_t)row*ld1 + (col-split); ld = ld1; }
      #pragma unroll
      for (int g = 0; g < 4; g++)
        D[(size_t)g*ld] = __float2bfloat16(acc[i][j][g] + bias);
    }
  }
}

// ---------------- logits MFMA: d_out[8192,17] = hbf @ WtLog^T + ofc_b (fp32 out) ----------------
__global__ __launch_bounds__(256)
void gemm_logits(const bf16* __restrict__ A, const bf16* __restrict__ Wt,
                 const float* __restrict__ bias, float* __restrict__ C){
  const int K = 512;
  __shared__ bf16 As[128*32];
  __shared__ bf16 Bs[128*32];
  int t = threadIdx.x;
  int wave = t >> 6, lane = t & 63;
  int bm = blockIdx.y * 128;
  int wm = (wave & 1) * 64, wn = (wave >> 1) * 64;
  ffrag acc[4][4];
  #pragma unroll
  for (int i = 0; i < 4; i++)
    #pragma unroll
    for (int j = 0; j < 4; j++) acc[i][j] = (ffrag){0.f,0.f,0.f,0.f};

  int srow = t >> 2;
  int scol = (t & 3) * 8;
  const bf16* gA = A  + (size_t)(bm + srow)*K + scol;
  const bf16* gB = Wt + (size_t)srow*K + scol;
  char* lA = (char*)As + 16*t;
  char* lB = (char*)Bs + 16*t;
  int q = lane >> 4, r = lane & 15;

  for (int k0 = 0; k0 < K; k0 += 32){
    gld16(gA + k0,          lA);
    gld16(gA + 64*K + k0,   lA + 4096);
    gld16(gB + k0,          lB);
    gld16(gB + 64*K + k0,   lB + 4096);
    __syncthreads();
    bfrag af[4], bfv[4];
    #pragma unroll
    for (int i = 0; i < 4; i++){
      af[i]  = *(const bfrag*)(As + (wm + i*16 + r)*32 + q*8);
      bfv[i] = *(const bfrag*)(Bs + (wn + i*16 + r)*32 + q*8);
    }
    #pragma unroll
    for (int i = 0; i < 4; i++)
      #pragma unroll
      for (int j = 0; j < 4; j++)
        acc[i][j] = __builtin_amdgcn_mfma_f32_16x16x32_bf16(af[i], bfv[j], acc[i][j], 0, 0, 0);
    __syncthreads();
  }
  #pragma unroll
  for (int i = 0; i < 4; i++){
    #pragma unroll
    for (int j = 0; j < 4; j++){
      int row = bm + wm + i*16 + q*4;
      int col = wn + j*16 + r;
      if (col < TT){
        float bias_v = bias[col];
        #pragma unroll
        for (int g = 0; g < 4; g++)
          C[(size_t)(row + g)*TT + col] = acc[i][j][g] + bias_v;
      }
    }
  }
}

// ---------------- batched s-projections: 8-way split-k, 32-col chunks (fp32) ----------------
__global__ __launch_bounds__(256)
void s_proj(const float* __restrict__ A,
            const float* __restrict__ W0, const float* __restrict__ W1,
            const float* __restrict__ W2, const float* __restrict__ W3,
            const float* __restrict__ W4,
            const float* __restrict__ bias0, const float* __restrict__ bias1,
            const float* __restrict__ bias2, const float* __restrict__ bias3,
            const float* __restrict__ bias4,
            float* __restrict__ O0, float* __restrict__ O1,
            float* __restrict__ O2, float* __restrict__ O3,
            float* __restrict__ O4,
            int ldc0, int ldc1, int ldc2, int ldc3, int ldc4){
  __shared__ float part[8][32][17];
  int t = threadIdx.x;
  int n = t & 31, kg = t >> 5;
  int wi = blockIdx.x >> 4, ch = blockIdx.x & 15;
  const float* W  = (wi==0)?W0:(wi==1)?W1:(wi==2)?W2:(wi==3)?W3:W4;
  const float* bs = (wi==0)?bias0:(wi==1)?bias1:(wi==2)?bias2:(wi==3)?bias3:bias4;
  float* O  = (wi==0)?O0:(wi==1)?O1:(wi==2)?O2:(wi==3)?O3:O4;
  int ldc   = (wi==0)?ldc0:(wi==1)?ldc1:(wi==2)?ldc2:(wi==3)?ldc3:ldc4;
  int col = ch*32 + n;
  float acc[16];
  #pragma unroll
  for (int m = 0; m < 16; m++) acc[m] = 0.f;
  const float* Wp = W + (size_t)(kg*64)*512 + col;
  const float* Ap = A + kg*64;
  for (int k = 0; k < 64; k++){
    float w = Wp[(size_t)k*512];
    #pragma unroll
    for (int m = 0; m < 16; m++) acc[m] = fmaf(Ap[m*512 + k], w, acc[m]);
  }
  #pragma unroll
  for (int m = 0; m < 16; m++) part[kg][n][m] = acc[m];
  __syncthreads();
  for (int o = t; o < 512; o += 256){
    int m = o >> 5, nn = o & 31;
    float v = 0.f;
    #pragma unroll
    for (int g = 0; g < 8; g++) v += part[g][nn][m];
    O[(size_t)m*ldc + ch*32 + nn] = v + bs[ch*32 + nn];
  }
}

// ---------------- sat attention: parameterized Q / Kh / Vh pointers ----------------
__global__ void sat_attn(const bf16* __restrict__ qp, int sq,
                         const bf16* __restrict__ kp, const bf16* __restrict__ vp, int skv,
                         const bf16* __restrict__ KeVe, const float* __restrict__ KsVs,
                         bf16* __restrict__ ctx){
  int gw = blockIdx.x*(blockDim.x >> 6) + (threadIdx.x >> 6);
  int lane = threadIdx.x & 63;
  int hh = gw & (NHH-1);
  int t  = gw >> 3;
  int b = t >> 9, l = t & 511;
  int base = hh*HDD + lane;
  float qv = __bfloat162float(qp[(size_t)t*sq + base]);
  int t0 = (b << 9) | ((l + 1) & 511);
  int t2 = (b << 9) | (l == 0 ? 511 : 0);
  float k[5];
  k[0] = __bfloat162float(kp  [(size_t)t0*skv + base]);
  k[1] = __bfloat162float(kp  [(size_t)t *skv + base]);
  k[2] = __bfloat162float(kp  [(size_t)t2*skv + base]);
  k[3] = __bfloat162float(KeVe[(size_t)t *1024 + base]);
  k[4] = KsVs[(size_t)b *1024 + base];
  float sc[5];
  #pragma unroll
  for (int j = 0; j < 5; j++){
    float v = qv * k[j];
    #pragma unroll
    for (int off = 32; off; off >>= 1) v += __shfl_xor(v, off, 64);
    sc[j] = v * 0.125f;
  }
  float m = fmaxf(fmaxf(fmaxf(sc[0],sc[1]), fmaxf(sc[2],sc[3])), sc[4]);
  float p[5], den = 0.f;
  #pragma unroll
  for (int j = 0; j < 5; j++){ p[j] = __expf(sc[j]-m); den += p[j]; }
  float inv = 1.0f/den;
  float v0 = __bfloat162float(vp  [(size_t)t0*skv + base]);
  float v1 = __bfloat162float(vp  [(size_t)t *skv + base]);
  float v2 = __bfloat162float(vp  [(size_t)t2*skv + base]);
  float v3 = __bfloat162float(KeVe[(size_t)t *1024 + 512 + base]);
  float v4 = KsVs[(size_t)b *1024 + 512 + base];
  float o = (p[0]*v0 + p[1]*v1 + p[2]*v2 + p[3]*v3 + p[4]*v4) * inv;
  ctx[(size_t)t*DD + base] = __float2bfloat16(o);
}

// ---------------- rel attention pass 1 (bf16 KV, fp32 s-row) ----------------
__global__ __launch_bounds__(256)
void rel_part(const float* __restrict__ q, const float* __restrict__ Ksr,
              const float* __restrict__ Vsr, const bf16* __restrict__ KV,
              float* __restrict__ pws){
  int ch = blockIdx.x, hh = blockIdx.y, b = blockIdx.z;
  int t = threadIdx.x;
  int base = hh * HDD;
  __shared__ __align__(16) float qs[64];
  __shared__ float sc[RCK];
  __shared__ float red[256];
  __shared__ float part[4][64];
  int j0 = ch * RCK;
  int nk = min(513 - j0, RCK);
  if (t < 64) qs[t] = q[(size_t)b*DD + base + t];
  __syncthreads();
  if (t < nk){
    int j = j0 + t;
    float a = 0.f;
    if (j == 0){
      const float* kr = Ksr + (size_t)b*DD + base;
      #pragma unroll
      for (int d = 0; d < 64; d += 4){
        float4 k4 = *(const float4*)(kr + d);
        float4 q4 = *(const float4*)(qs + d);
        a += q4.x*k4.x + q4.y*k4.y + q4.z*k4.z + q4.w*k4.w;
      }
    } else {
      const bf16* kr = KV + ((size_t)b*LL + j - 1)*1024 + base;
      #pragma unroll
      for (int d = 0; d < 64; d += 8){
        us8 k8 = *(const us8*)(kr + d);
        #pragma unroll
        for (int g = 0; g < 8; g++) a += qs[d+g] * us2f(k8[g]);
      }
    }
    sc[t] = a * 0.125f;
  }
  __syncthreads();
  red[t] = (t < nk) ? sc[t] : -1e30f; __syncthreads();
  for (int st = 128; st; st >>= 1){ if (t < st) red[t] = fmaxf(red[t], red[t+st]); __syncthreads(); }
  float m = red[0]; __syncthreads();
  if (t < nk) sc[t] = __expf(sc[t] - m);
  __syncthreads();
  red[t] = (t < nk) ? sc[t] : 0.f; __syncthreads();
  for (int st = 128; st; st >>= 1){ if (t < st) red[t] += red[t+st]; __syncthreads(); }
  float l = red[0];
  int d = t & 63, c2 = t >> 6;
  float a = 0.f;
  for (int j = c2; j < nk; j += 4){
    int gj = j0 + j;
    float vv = (gj == 0) ? Vsr[(size_t)b*DD + base + d]
                         : __bfloat162float(KV[((size_t)b*LL + gj - 1)*1024 + 512 + base + d]);
    a += sc[j] * vv;
  }
  part[c2][d] = a; __syncthreads();
  float* o = pws + (((size_t)(b*NHH + hh))*RCH + ch) * 66;
  if (t < 64) o[t] = part[0][t] + part[1][t] + part[2][t] + part[3][t];
  else if (t == 64) o[64] = m;
  else if (t == 65) o[65] = l;
}

// ---------------- fused rel tail: combine chunks -> out-proj -> relu+LN -> s ----------------
// grid = BB blocks, 256 threads
__global__ __launch_bounds__(256)
void rel_tail(const float* __restrict__ pws, const float* __restrict__ W,
              const float* __restrict__ bias, const float* __restrict__ lnw,
              const float* __restrict__ lnb, float* __restrict__ s){
  int b = blockIdx.x;
  int t = threadIdx.x;
  __shared__ float crs[512];
  __shared__ float red[256];
  for (int o = t; o < 512; o += 256){
    int hh = o >> 6, d = o & 63;
    const float* p = pws + ((size_t)(b*NHH + hh))*RCH*66;
    float M = -1e30f;
    #pragma unroll
    for (int c = 0; c < RCH; c++) M = fmaxf(M, p[c*66 + 64]);
    float den = 0.f, acc = 0.f;
    #pragma unroll
    for (int c = 0; c < RCH; c++){
      float w = __expf(p[c*66 + 64] - M);
      den += w * p[c*66 + 65];
      acc += w * p[c*66 + d];
    }
    crs[o] = acc / den;
  }
  __syncthreads();
  int n0 = t, n1 = t + 256;
  float a0 = 0.f, a1 = 0.f;
  for (int k = 0; k < 512; k++){
    float c = crs[k];
    a0 = fmaf(c, W[(size_t)k*512 + n0], a0);
    a1 = fmaf(c, W[(size_t)k*512 + n1], a1);
  }
  a0 += bias[n0]; a1 += bias[n1];
  float v0 = fmaxf(a0, 0.f), v1 = fmaxf(a1, 0.f);
  red[t] = v0 + v1; __syncthreads();
  for (int st = 128; st; st >>= 1){ if (t < st) red[t] += red[t+st]; __syncthreads(); }
  float u = red[0] * (1.0f/DD); __syncthreads();
  float d0 = v0 - u, d1 = v1 - u;
  red[t] = d0*d0 + d1*d1; __syncthreads();
  for (int st = 128; st; st >>= 1){ if (t < st) red[t] += red[t+st]; __syncthreads(); }
  float inv = rsqrtf(red[0] * (1.0f/DD) + 1e-12f);
  // s MUST be written — it feeds the next cycle (round-5 lesson).
  s[(size_t)b*DD + n0] = lnw[n0]*d0*inv + lnb[n0];
  s[(size_t)b*DD + n1] = lnw[n1]*d1*inv + lnb[n1];
}

// ---------------- h path: y = ln(relu(x)), bf16 in -> bf16 out ----------------
__global__ void relu_ln_bf(const bf16* __restrict__ X, const float* __restrict__ w,
                           const float* __restrict__ bn, bf16* __restrict__ Ybf){
  int row = blockIdx.x;
  int tid = threadIdx.x; // 256
  __shared__ float red[256];
  const bf16* x = X + (size_t)row*DD;
  float v0 = fmaxf(__bfloat162float(x[tid]), 0.f);
  float v1 = fmaxf(__bfloat162float(x[tid+256]), 0.f);
  red[tid] = v0 + v1;
  __syncthreads();
  for (int st = 128; st; st >>= 1){ if (tid < st) red[tid] += red[tid+st]; __syncthreads(); }
  float u = red[0] * (1.0f/DD);
  __syncthreads();
  float d0 = v0 - u, d1 = v1 - u;
  red[tid] = d0*d0 + d1*d1;
  __syncthreads();
  for (int st = 128; st; st >>= 1){ if (tid < st) red[tid] += red[tid+st]; __syncthreads(); }
  float var = red[0] * (1.0f/DD);
  float inv = rsqrtf(var + 1e-12f);
  Ybf[(size_t)row*DD + tid]       = __float2bfloat16(w[tid]    *d0*inv + bn[tid]);
  Ybf[(size_t)row*DD + tid + 256] = __float2bfloat16(w[tid+256]*d1*inv + bn[tid+256]);
}

extern "C" void kernel_launch(void* const* d_in, const int* in_sizes, int n_in,
                              void* d_out, int out_size, void* d_ws, size_t ws_size,
                              hipStream_t stream) {
  const int*   tokens  = (const int*)  d_in[0];
  const float* emb     = (const float*)d_in[4];
  const float* sat_qw  = (const float*)d_in[5];
  const float* sat_qb  = (const float*)d_in[6];
  const float* sat_kw  = (const float*)d_in[7];
  const float* sat_kb  = (const float*)d_in[8];
  const float* sat_vw  = (const float*)d_in[9];
  const float* sat_vb  = (const float*)d_in[10];
  const float* sat_ow  = (const float*)d_in[11];
  const float* sat_ob  = (const float*)d_in[12];
  const float* rel_qw  = (const float*)d_in[13];
  const float* rel_qb  = (const float*)d_in[14];
  const float* rel_kw  = (const float*)d_in[15];
  const float* rel_kb  = (const float*)d_in[16];
  const float* rel_vw  = (const float*)d_in[17];
  const float* rel_vb  = (const float*)d_in[18];
  const float* rel_ow  = (const float*)d_in[19];
  const float* rel_ob  = (const float*)d_in[20];
  const float* ln_sat_w= (const float*)d_in[21];
  const float* ln_sat_b= (const float*)d_in[22];
  const float* ln_rel_w= (const float*)d_in[23];
  const float* ln_rel_b= (const float*)d_in[24];
  const float* ofc_w   = (const float*)d_in[25];
  const float* ofc_b   = (const float*)d_in[26];

  char* p = (char*)d_ws;
  auto alloc = [&](size_t bytes) -> char* {
    char* r = p; p += (bytes + 255) & ~(size_t)255; return r;
  };
  const size_t BIGH = (size_t)MM*DD*2;          // 8 MB (bf16 M x 512)
  bf16*  ebf   = (bf16*) alloc(BIGH);           // e bf16; later reused as hbf
  bf16*  qkv   = (bf16*) alloc(3*BIGH);         // [M,1536] bf16; aliased: aout + kv
  bf16*  KeVe  = (bf16*) alloc(2*BIGH);         // [M,1024] bf16 (persists)
  bf16*  qbuf  = (bf16*) alloc(BIGH);           // cycle-0 Q [M,512]
  bf16*  ctxbf = (bf16*) alloc(BIGH);
  bf16*  WtSat = (bf16*) alloc((size_t)1536*512*2);
  bf16*  WtRel = (bf16*) alloc((size_t)1024*512*2);
  bf16*  WtO   = (bf16*) alloc((size_t)512*512*2);
  bf16*  WtLog = (bf16*) alloc((size_t)128*512*2);
  float* s     = (float*)alloc(BB*DD*4);
  float* KsVs  = (float*)alloc(BB*1024*4);
  float* qr    = (float*)alloc(BB*DD*4);
  float* Ksr   = (float*)alloc(BB*DD*4);
  float* Vsr   = (float*)alloc(BB*DD*4);
  float* mpart = (float*)alloc((size_t)256*DD*4);          // mean partials
  float* pws   = (float*)alloc((size_t)BB*NHH*RCH*66*4);   // rel partials
  bf16*  hbf   = ebf;                           // reuse: e_bf dead after cycle-0 Q+KeVe+mean
  bf16*  aout  = qkv;                           // reuse
  bf16*  kv    = qkv + (size_t)MM*512;          // [M,1024] bf16 inside qkv region

  int total = MM*DD;

  embed_kernel<<<(total+255)/256, 256, 0, stream>>>(tokens, emb, ebf, total);
  mean1<<<256, 256, 0, stream>>>(ebf, mpart);
  mean2<<<32, 256, 0, stream>>>(mpart, s);

  prep_w<<<dim3(16,16,6), dim3(32,8), 0, stream>>>(
      sat_qw, sat_kw, sat_vw, rel_kw, rel_vw, sat_ow,
      WtSat, WtSat + (size_t)512*512, WtSat + (size_t)1024*512,
      WtRel, WtRel + (size_t)512*512, WtO);
  pad_logw<<<256, 256, 0, stream>>>(ofc_w, WtLog);

  for (int c = 0; c < 2; c++){
    const bf16 *qp, *kp, *vp; int sq, skv;
    if (c == 0){
      // fused: Q -> qbuf, K|V -> KeVe (persists; doubles as Kh/Vh since h==e)
      gemm_mfma_bf<<<dim3(12,64), 256, 0, stream>>>(ebf, WtSat,
          sat_qb, sat_kb, sat_vb, qbuf, 512, KeVe, 1024, 512);
      qp = qbuf; sq = 512; kp = KeVe; vp = KeVe + 512; skv = 1024;
    } else {
      gemm_mfma_bf<<<dim3(12,64), 256, 0, stream>>>(hbf, WtSat,
          sat_qb, sat_kb, sat_vb, qkv, 1536, qkv, 1536, 1536);
      qp = qkv; sq = 1536; kp = qkv + 512; vp = qkv + 1024; skv = 1536;
    }
    s_proj<<<80, 256, 0, stream>>>(s,
        sat_kw, sat_vw, rel_qw, rel_kw, rel_vw,
        sat_kb, sat_vb, rel_qb, rel_kb, rel_vb,
        KsVs, KsVs + 512, qr, Ksr, Vsr,
        1024, 1024, 512, 512, 512);
    sat_attn<<<MM*NHH/4, 256, 0, stream>>>(qp, sq, kp, vp, skv, KeVe, KsVs, ctxbf);
    gemm_mfma_bf<<<dim3(4,64), 256, 0, stream>>>(ctxbf, WtO,
        sat_ob, sat_ob, sat_ob, aout, 512, aout, 512, 512);
    relu_ln_bf<<<MM, 256, 0, stream>>>(aout, ln_sat_w, ln_sat_b, hbf);
    gemm_mfma_bf<<<dim3(8,64), 256, 0, stream>>>(hbf, WtRel,
        rel_kb, rel_vb, rel_vb, kv, 1024, kv, 1024, 1024);
    rel_part<<<dim3(RCH, NHH, BB), 256, 0, stream>>>(qr, Ksr, Vsr, kv, pws);
    rel_tail<<<BB, 256, 0, stream>>>(pws, rel_ow, rel_ob, ln_rel_w, ln_rel_b, s);
  }

  gemm_logits<<<dim3(1,64), 256, 0, stream>>>(hbf, WtLog, ofc_b, (float*)d_out);
}

// Round 10
// 376.916 us; speedup vs baseline: 1.1979x; 1.1979x over previous
//
#include <hip/hip_runtime.h>
#include <hip/hip_bf16.h>

typedef __hip_bfloat16 bf16;

#define BB 16
#define LL 512
#define DD 512
#define NHH 8
#define HDD 64
#define TT 17
#define MM (BB*LL)   // 8192 rows
#define RCH 8        // rel-attn key chunks
#define RCK 65       // keys per chunk (8*65=520 >= 513)

typedef __attribute__((ext_vector_type(8))) short bfrag;   // 8 bf16
typedef __attribute__((ext_vector_type(4))) float ffrag;   // 4 fp32
typedef __attribute__((ext_vector_type(8))) unsigned short us8;

static __device__ __forceinline__ void gld16(const void* g, void* l){
  __builtin_amdgcn_global_load_lds((const __attribute__((address_space(1))) void*)g,
                                   (__attribute__((address_space(3))) void*)l, 16, 0, 0);
}
static __device__ __forceinline__ float us2f(unsigned short u){
  unsigned int v = ((unsigned int)u) << 16;
  float f; __builtin_memcpy(&f, &v, 4); return f;
}

// ---------------- fused embed gather + mean partial sums ----------------
// grid 256 = (b, 32-row chunk); writes ebf and per-chunk column sums
__global__ __launch_bounds__(256)
void emean(const int* __restrict__ tokens, const float* __restrict__ emb,
           bf16* __restrict__ ebf, float* __restrict__ mpart){
  int blk = blockIdx.x;
  int b = blk >> 4, lc = blk & 15;
  int t = threadIdx.x;
  __shared__ int toks[32];
  if (t < 32) toks[t] = tokens[b*LL + lc*32 + t];
  __syncthreads();
  bf16* eb = ebf + ((size_t)b*LL + lc*32)*DD;
  for (int d = t; d < DD; d += 256){
    float acc = 0.f;
    #pragma unroll 4
    for (int l = 0; l < 32; l++){
      float v = emb[(size_t)toks[l]*DD + d];
      eb[(size_t)l*DD + d] = __float2bfloat16(v);
      acc += v;
    }
    mpart[(size_t)blk*DD + d] = acc;
  }
}
// ---------------- mean stage 2 ----------------
__global__ void mean2(const float* __restrict__ part, float* __restrict__ s){
  int i = blockIdx.x*256 + threadIdx.x;   // 8192
  int b = i >> 9, d = i & 511;
  float acc = 0.f;
  #pragma unroll
  for (int c = 0; c < 16; c++) acc += part[(size_t)(b*16 + c)*DD + d];
  s[i] = acc * (1.0f/LL);
}

// ---------------- weight prep: 6x transpose->bf16 + padded logits W, one launch ----------------
__global__ void prep_w(const float* __restrict__ i0, const float* __restrict__ i1,
                       const float* __restrict__ i2, const float* __restrict__ i3,
                       const float* __restrict__ i4, const float* __restrict__ i5,
                       const float* __restrict__ wlog,
                       bf16* __restrict__ o0, bf16* __restrict__ o1,
                       bf16* __restrict__ o2, bf16* __restrict__ o3,
                       bf16* __restrict__ o4, bf16* __restrict__ o5,
                       bf16* __restrict__ olog){
  int z = blockIdx.z;
  int tx = threadIdx.x, ty = threadIdx.y;       // 32 x 8
  if (z == 6){
    // logits W: 512x17 -> 128x512 transposed zero-padded; 256 blocks x 256 thr
    int tid = ty*32 + tx;
    int i = ((blockIdx.y*16 + blockIdx.x) << 8) + tid;   // 0..65535
    int row = i >> 9, k = i & 511;
    olog[i] = __float2bfloat16(row < TT ? wlog[(size_t)k*TT + row] : 0.f);
    return;
  }
  __shared__ float tile[32][33];
  const float* in = (z==0)?i0:(z==1)?i1:(z==2)?i2:(z==3)?i3:(z==4)?i4:i5;
  bf16* out       = (z==0)?o0:(z==1)?o1:(z==2)?o2:(z==3)?o3:(z==4)?o4:o5;
  int bx = blockIdx.x*32, by = blockIdx.y*32;
  #pragma unroll
  for (int j = 0; j < 32; j += 8)
    tile[ty + j][tx] = in[(size_t)(by + ty + j)*DD + bx + tx];
  __syncthreads();
  #pragma unroll
  for (int j = 0; j < 32; j += 8)
    out[(size_t)(bx + ty + j)*DD + by + tx] = __float2bfloat16(tile[tx][ty + j]);
}

// ---------------- MFMA GEMM, bf16 output, split destination, 5 bias chunks ----------------
__global__ __launch_bounds__(256)
void gemm_mfma_bf(const bf16* __restrict__ A, const bf16* __restrict__ Wt,
                  const float* __restrict__ b0, const float* __restrict__ b1,
                  const float* __restrict__ b2, const float* __restrict__ b3,
                  const float* __restrict__ b4,
                  bf16* __restrict__ D0, int ld0,
                  bf16* __restrict__ D1, int ld1, int split){
  const int K = 512;
  __shared__ bf16 As[128*32];
  __shared__ bf16 Bs[128*32];
  int t = threadIdx.x;
  int wave = t >> 6, lane = t & 63;
  int bm = blockIdx.y * 128, bn = blockIdx.x * 128;
  int wm = (wave & 1) * 64, wn = (wave >> 1) * 64;
  ffrag acc[4][4];
  #pragma unroll
  for (int i = 0; i < 4; i++)
    #pragma unroll
    for (int j = 0; j < 4; j++) acc[i][j] = (ffrag){0.f,0.f,0.f,0.f};

  int srow = t >> 2;
  int scol = (t & 3) * 8;
  const bf16* gA = A  + (size_t)(bm + srow)*K + scol;
  const bf16* gB = Wt + (size_t)(bn + srow)*K + scol;
  char* lA = (char*)As + 16*t;
  char* lB = (char*)Bs + 16*t;
  int q = lane >> 4, r = lane & 15;

  for (int k0 = 0; k0 < K; k0 += 32){
    gld16(gA + k0,          lA);
    gld16(gA + 64*K + k0,   lA + 4096);
    gld16(gB + k0,          lB);
    gld16(gB + 64*K + k0,   lB + 4096);
    __syncthreads();
    bfrag af[4], bfv[4];
    #pragma unroll
    for (int i = 0; i < 4; i++){
      af[i]  = *(const bfrag*)(As + (wm + i*16 + r)*32 + q*8);
      bfv[i] = *(const bfrag*)(Bs + (wn + i*16 + r)*32 + q*8);
    }
    #pragma unroll
    for (int i = 0; i < 4; i++)
      #pragma unroll
      for (int j = 0; j < 4; j++)
        acc[i][j] = __builtin_amdgcn_mfma_f32_16x16x32_bf16(af[i], bfv[j], acc[i][j], 0, 0, 0);
    __syncthreads();
  }
  #pragma unroll
  for (int i = 0; i < 4; i++){
    #pragma unroll
    for (int j = 0; j < 4; j++){
      int row = bm + wm + i*16 + q*4;
      int col = bn + wn + j*16 + r;
      const float* bp = (col < 512) ? b0 : (col < 1024) ? b1 :
                        (col < 1536) ? b2 : (col < 2048) ? b3 : b4;
      float bias = bp[col & 511];
      bf16* D; int ld;
      if (col < split){ D = D0 + (size_t)row*ld0 + col;         ld = ld0; }
      else            { D = D1 + (size_t)row*ld1 + (col-split); ld = ld1; }
      #pragma unroll
      for (int g = 0; g < 4; g++)
        D[(size_t)g*ld] = __float2bfloat16(acc[i][j][g] + bias);
    }
  }
}

// ---------------- logits MFMA: d_out[8192,17] = hbf @ WtLog^T + ofc_b (fp32 out) ----------------
__global__ __launch_bounds__(256)
void gemm_logits(const bf16* __restrict__ A, const bf16* __restrict__ Wt,
                 const float* __restrict__ bias, float* __restrict__ C){
  const int K = 512;
  __shared__ bf16 As[128*32];
  __shared__ bf16 Bs[128*32];
  int t = threadIdx.x;
  int wave = t >> 6, lane = t & 63;
  int bm = blockIdx.y * 128;
  int wm = (wave & 1) * 64, wn = (wave >> 1) * 64;
  ffrag acc[4][4];
  #pragma unroll
  for (int i = 0; i < 4; i++)
    #pragma unroll
    for (int j = 0; j < 4; j++) acc[i][j] = (ffrag){0.f,0.f,0.f,0.f};

  int srow = t >> 2;
  int scol = (t & 3) * 8;
  const bf16* gA = A  + (size_t)(bm + srow)*K + scol;
  const bf16* gB = Wt + (size_t)srow*K + scol;
  char* lA = (char*)As + 16*t;
  char* lB = (char*)Bs + 16*t;
  int q = lane >> 4, r = lane & 15;

  for (int k0 = 0; k0 < K; k0 += 32){
    gld16(gA + k0,          lA);
    gld16(gA + 64*K + k0,   lA + 4096);
    gld16(gB + k0,          lB);
    gld16(gB + 64*K + k0,   lB + 4096);
    __syncthreads();
    bfrag af[4], bfv[4];
    #pragma unroll
    for (int i = 0; i < 4; i++){
      af[i]  = *(const bfrag*)(As + (wm + i*16 + r)*32 + q*8);
      bfv[i] = *(const bfrag*)(Bs + (wn + i*16 + r)*32 + q*8);
    }
    #pragma unroll
    for (int i = 0; i < 4; i++)
      #pragma unroll
      for (int j = 0; j < 4; j++)
        acc[i][j] = __builtin_amdgcn_mfma_f32_16x16x32_bf16(af[i], bfv[j], acc[i][j], 0, 0, 0);
    __syncthreads();
  }
  #pragma unroll
  for (int i = 0; i < 4; i++){
    #pragma unroll
    for (int j = 0; j < 4; j++){
      int row = bm + wm + i*16 + q*4;
      int col = wn + j*16 + r;
      if (col < TT){
        float bias_v = bias[col];
        #pragma unroll
        for (int g = 0; g < 4; g++)
          C[(size_t)(row + g)*TT + col] = acc[i][j][g] + bias_v;
      }
    }
  }
}

// ---------------- batched s-projections: 8-way split-k, 32-col chunks (fp32) ----------------
__global__ __launch_bounds__(256)
void s_proj(const float* __restrict__ A,
            const float* __restrict__ W0, const float* __restrict__ W1,
            const float* __restrict__ W2, const float* __restrict__ W3,
            const float* __restrict__ W4,
            const float* __restrict__ bias0, const float* __restrict__ bias1,
            const float* __restrict__ bias2, const float* __restrict__ bias3,
            const float* __restrict__ bias4,
            float* __restrict__ O0, float* __restrict__ O1,
            float* __restrict__ O2, float* __restrict__ O3,
            float* __restrict__ O4,
            int ldc0, int ldc1, int ldc2, int ldc3, int ldc4){
  __shared__ float part[8][32][17];
  int t = threadIdx.x;
  int n = t & 31, kg = t >> 5;
  int wi = blockIdx.x >> 4, ch = blockIdx.x & 15;
  const float* W  = (wi==0)?W0:(wi==1)?W1:(wi==2)?W2:(wi==3)?W3:W4;
  const float* bs = (wi==0)?bias0:(wi==1)?bias1:(wi==2)?bias2:(wi==3)?bias3:bias4;
  float* O  = (wi==0)?O0:(wi==1)?O1:(wi==2)?O2:(wi==3)?O3:O4;
  int ldc   = (wi==0)?ldc0:(wi==1)?ldc1:(wi==2)?ldc2:(wi==3)?ldc3:ldc4;
  int col = ch*32 + n;
  float acc[16];
  #pragma unroll
  for (int m = 0; m < 16; m++) acc[m] = 0.f;
  const float* Wp = W + (size_t)(kg*64)*512 + col;
  const float* Ap = A + kg*64;
  for (int k = 0; k < 64; k++){
    float w = Wp[(size_t)k*512];
    #pragma unroll
    for (int m = 0; m < 16; m++) acc[m] = fmaf(Ap[m*512 + k], w, acc[m]);
  }
  #pragma unroll
  for (int m = 0; m < 16; m++) part[kg][n][m] = acc[m];
  __syncthreads();
  for (int o = t; o < 512; o += 256){
    int m = o >> 5, nn = o & 31;
    float v = 0.f;
    #pragma unroll
    for (int g = 0; g < 8; g++) v += part[g][nn][m];
    O[(size_t)m*ldc + ch*32 + nn] = v + bs[ch*32 + nn];
  }
}

// ---------------- sat attention: parameterized Q / Kh / Vh pointers ----------------
__global__ void sat_attn(const bf16* __restrict__ qp, int sq,
                         const bf16* __restrict__ kp, const bf16* __restrict__ vp, int skv,
                         const bf16* __restrict__ KeVe, const float* __restrict__ KsVs,
                         bf16* __restrict__ ctx){
  int gw = blockIdx.x*(blockDim.x >> 6) + (threadIdx.x >> 6);
  int lane = threadIdx.x & 63;
  int hh = gw & (NHH-1);
  int t  = gw >> 3;
  int b = t >> 9, l = t & 511;
  int base = hh*HDD + lane;
  float qv = __bfloat162float(qp[(size_t)t*sq + base]);
  int t0 = (b << 9) | ((l + 1) & 511);
  int t2 = (b << 9) | (l == 0 ? 511 : 0);
  float k[5];
  k[0] = __bfloat162float(kp  [(size_t)t0*skv + base]);
  k[1] = __bfloat162float(kp  [(size_t)t *skv + base]);
  k[2] = __bfloat162float(kp  [(size_t)t2*skv + base]);
  k[3] = __bfloat162float(KeVe[(size_t)t *1024 + base]);
  k[4] = KsVs[(size_t)b *1024 + base];
  float sc[5];
  #pragma unroll
  for (int j = 0; j < 5; j++){
    float v = qv * k[j];
    #pragma unroll
    for (int off = 32; off; off >>= 1) v += __shfl_xor(v, off, 64);
    sc[j] = v * 0.125f;
  }
  float m = fmaxf(fmaxf(fmaxf(sc[0],sc[1]), fmaxf(sc[2],sc[3])), sc[4]);
  float p[5], den = 0.f;
  #pragma unroll
  for (int j = 0; j < 5; j++){ p[j] = __expf(sc[j]-m); den += p[j]; }
  float inv = 1.0f/den;
  float v0 = __bfloat162float(vp  [(size_t)t0*skv + base]);
  float v1 = __bfloat162float(vp  [(size_t)t *skv + base]);
  float v2 = __bfloat162float(vp  [(size_t)t2*skv + base]);
  float v3 = __bfloat162float(KeVe[(size_t)t *1024 + 512 + base]);
  float v4 = KsVs[(size_t)b *1024 + 512 + base];
  float o = (p[0]*v0 + p[1]*v1 + p[2]*v2 + p[3]*v3 + p[4]*v4) * inv;
  ctx[(size_t)t*DD + base] = __float2bfloat16(o);
}

// ---------------- rel attention pass 1 (bf16 KV, fp32 s-row) ----------------
__global__ __launch_bounds__(256)
void rel_part(const float* __restrict__ q, const float* __restrict__ Ksr,
              const float* __restrict__ Vsr, const bf16* __restrict__ KV,
              float* __restrict__ pws){
  int ch = blockIdx.x, hh = blockIdx.y, b = blockIdx.z;
  int t = threadIdx.x;
  int base = hh * HDD;
  __shared__ __align__(16) float qs[64];
  __shared__ float sc[RCK];
  __shared__ float red[256];
  __shared__ float part[4][64];
  int j0 = ch * RCK;
  int nk = min(513 - j0, RCK);
  if (t < 64) qs[t] = q[(size_t)b*DD + base + t];
  __syncthreads();
  if (t < nk){
    int j = j0 + t;
    float a = 0.f;
    if (j == 0){
      const float* kr = Ksr + (size_t)b*DD + base;
      #pragma unroll
      for (int d = 0; d < 64; d += 4){
        float4 k4 = *(const float4*)(kr + d);
        float4 q4 = *(const float4*)(qs + d);
        a += q4.x*k4.x + q4.y*k4.y + q4.z*k4.z + q4.w*k4.w;
      }
    } else {
      const bf16* kr = KV + ((size_t)b*LL + j - 1)*1024 + base;
      #pragma unroll
      for (int d = 0; d < 64; d += 8){
        us8 k8 = *(const us8*)(kr + d);
        #pragma unroll
        for (int g = 0; g < 8; g++) a += qs[d+g] * us2f(k8[g]);
      }
    }
    sc[t] = a * 0.125f;
  }
  __syncthreads();
  red[t] = (t < nk) ? sc[t] : -1e30f; __syncthreads();
  for (int st = 128; st; st >>= 1){ if (t < st) red[t] = fmaxf(red[t], red[t+st]); __syncthreads(); }
  float m = red[0]; __syncthreads();
  if (t < nk) sc[t] = __expf(sc[t] - m);
  __syncthreads();
  red[t] = (t < nk) ? sc[t] : 0.f; __syncthreads();
  for (int st = 128; st; st >>= 1){ if (t < st) red[t] += red[t+st]; __syncthreads(); }
  float l = red[0];
  int d = t & 63, c2 = t >> 6;
  float a = 0.f;
  for (int j = c2; j < nk; j += 4){
    int gj = j0 + j;
    float vv = (gj == 0) ? Vsr[(size_t)b*DD + base + d]
                         : __bfloat162float(KV[((size_t)b*LL + gj - 1)*1024 + 512 + base + d]);
    a += sc[j] * vv;
  }
  part[c2][d] = a; __syncthreads();
  float* o = pws + (((size_t)(b*NHH + hh))*RCH + ch) * 66;
  if (t < 64) o[t] = part[0][t] + part[1][t] + part[2][t] + part[3][t];
  else if (t == 64) o[64] = m;
  else if (t == 65) o[65] = l;
}

// ---------------- fused rel tail: combine chunks -> out-proj -> relu+LN -> s ----------------
__global__ __launch_bounds__(256)
void rel_tail(const float* __restrict__ pws, const float* __restrict__ W,
              const float* __restrict__ bias, const float* __restrict__ lnw,
              const float* __restrict__ lnb, float* __restrict__ s){
  int b = blockIdx.x;
  int t = threadIdx.x;
  __shared__ float crs[512];
  __shared__ float red[256];
  for (int o = t; o < 512; o += 256){
    int hh = o >> 6, d = o & 63;
    const float* p = pws + ((size_t)(b*NHH + hh))*RCH*66;
    float M = -1e30f;
    #pragma unroll
    for (int c = 0; c < RCH; c++) M = fmaxf(M, p[c*66 + 64]);
    float den = 0.f, acc = 0.f;
    #pragma unroll
    for (int c = 0; c < RCH; c++){
      float w = __expf(p[c*66 + 64] - M);
      den += w * p[c*66 + 65];
      acc += w * p[c*66 + d];
    }
    crs[o] = acc / den;
  }
  __syncthreads();
  int n0 = t, n1 = t + 256;
  float a0 = 0.f, a1 = 0.f;
  for (int k = 0; k < 512; k++){
    float c = crs[k];
    a0 = fmaf(c, W[(size_t)k*512 + n0], a0);
    a1 = fmaf(c, W[(size_t)k*512 + n1], a1);
  }
  a0 += bias[n0]; a1 += bias[n1];
  float v0 = fmaxf(a0, 0.f), v1 = fmaxf(a1, 0.f);
  red[t] = v0 + v1; __syncthreads();
  for (int st = 128; st; st >>= 1){ if (t < st) red[t] += red[t+st]; __syncthreads(); }
  float u = red[0] * (1.0f/DD); __syncthreads();
  float d0 = v0 - u, d1 = v1 - u;
  red[t] = d0*d0 + d1*d1; __syncthreads();
  for (int st = 128; st; st >>= 1){ if (t < st) red[t] += red[t+st]; __syncthreads(); }
  float inv = rsqrtf(red[0] * (1.0f/DD) + 1e-12f);
  // s MUST be written — it feeds the next cycle (round-5 lesson).
  s[(size_t)b*DD + n0] = lnw[n0]*d0*inv + lnb[n0];
  s[(size_t)b*DD + n1] = lnw[n1]*d1*inv + lnb[n1];
}

// ---------------- h path: y = ln(relu(x)), bf16 in -> bf16 out ----------------
__global__ void relu_ln_bf(const bf16* __restrict__ X, const float* __restrict__ w,
                           const float* __restrict__ bn, bf16* __restrict__ Ybf){
  int row = blockIdx.x;
  int tid = threadIdx.x; // 256
  __shared__ float red[256];
  const bf16* x = X + (size_t)row*DD;
  float v0 = fmaxf(__bfloat162float(x[tid]), 0.f);
  float v1 = fmaxf(__bfloat162float(x[tid+256]), 0.f);
  red[tid] = v0 + v1;
  __syncthreads();
  for (int st = 128; st; st >>= 1){ if (tid < st) red[tid] += red[tid+st]; __syncthreads(); }
  float u = red[0] * (1.0f/DD);
  __syncthreads();
  float d0 = v0 - u, d1 = v1 - u;
  red[tid] = d0*d0 + d1*d1;
  __syncthreads();
  for (int st = 128; st; st >>= 1){ if (tid < st) red[tid] += red[tid+st]; __syncthreads(); }
  float var = red[0] * (1.0f/DD);
  float inv = rsqrtf(var + 1e-12f);
  Ybf[(size_t)row*DD + tid]       = __float2bfloat16(w[tid]    *d0*inv + bn[tid]);
  Ybf[(size_t)row*DD + tid + 256] = __float2bfloat16(w[tid+256]*d1*inv + bn[tid+256]);
}

extern "C" void kernel_launch(void* const* d_in, const int* in_sizes, int n_in,
                              void* d_out, int out_size, void* d_ws, size_t ws_size,
                              hipStream_t stream) {
  const int*   tokens  = (const int*)  d_in[0];
  const float* emb     = (const float*)d_in[4];
  const float* sat_qw  = (const float*)d_in[5];
  const float* sat_qb  = (const float*)d_in[6];
  const float* sat_kw  = (const float*)d_in[7];
  const float* sat_kb  = (const float*)d_in[8];
  const float* sat_vw  = (const float*)d_in[9];
  const float* sat_vb  = (const float*)d_in[10];
  const float* sat_ow  = (const float*)d_in[11];
  const float* sat_ob  = (const float*)d_in[12];
  const float* rel_qw  = (const float*)d_in[13];
  const float* rel_qb  = (const float*)d_in[14];
  const float* rel_kw  = (const float*)d_in[15];
  const float* rel_kb  = (const float*)d_in[16];
  const float* rel_vw  = (const float*)d_in[17];
  const float* rel_vb  = (const float*)d_in[18];
  const float* rel_ow  = (const float*)d_in[19];
  const float* rel_ob  = (const float*)d_in[20];
  const float* ln_sat_w= (const float*)d_in[21];
  const float* ln_sat_b= (const float*)d_in[22];
  const float* ln_rel_w= (const float*)d_in[23];
  const float* ln_rel_b= (const float*)d_in[24];
  const float* ofc_w   = (const float*)d_in[25];
  const float* ofc_b   = (const float*)d_in[26];

  char* p = (char*)d_ws;
  auto alloc = [&](size_t bytes) -> char* {
    char* r = p; p += (bytes + 255) & ~(size_t)255; return r;
  };
  const size_t BIGH = (size_t)MM*DD*2;          // 8 MB (bf16 M x 512)
  bf16*  ebf   = (bf16*) alloc(BIGH);           // e bf16; later reused as hbf
  bf16*  qkv   = (bf16*) alloc(3*BIGH);         // [M,1536] bf16; aliased: aout
  bf16*  kvbuf = (bf16*) alloc(2*BIGH);         // [M,1024] rel K|V (cycle 0)
  bf16*  KeVe  = (bf16*) alloc(2*BIGH);         // [M,1024] bf16 (persists)
  bf16*  qbuf  = (bf16*) alloc(BIGH);           // cycle-0 Q [M,512]
  bf16*  ctxbf = (bf16*) alloc(BIGH);
  bf16*  WtAll = (bf16*) alloc((size_t)2560*512*2);  // sat_q|sat_k|sat_v|rel_k|rel_v ^T
  bf16*  WtO   = (bf16*) alloc((size_t)512*512*2);
  bf16*  WtLog = (bf16*) alloc((size_t)128*512*2);
  float* s     = (float*)alloc(BB*DD*4);
  float* KsVs  = (float*)alloc(BB*1024*4);
  float* qr    = (float*)alloc(BB*DD*4);
  float* Ksr   = (float*)alloc(BB*DD*4);
  float* Vsr   = (float*)alloc(BB*DD*4);
  float* mpart = (float*)alloc((size_t)256*DD*4);          // mean partials
  float* pws   = (float*)alloc((size_t)BB*NHH*RCH*66*4);   // rel partials
  bf16*  hbf   = ebf;                           // reuse: e_bf dead after cycle-0 Q/KeVe/mean
  bf16*  aout  = qkv;                           // reuse: qkv region between uses

  emean<<<256, 256, 0, stream>>>(tokens, emb, ebf, mpart);
  mean2<<<32, 256, 0, stream>>>(mpart, s);

  prep_w<<<dim3(16,16,7), dim3(32,8), 0, stream>>>(
      sat_qw, sat_kw, sat_vw, rel_kw, rel_vw, sat_ow, ofc_w,
      WtAll, WtAll + (size_t)512*512, WtAll + (size_t)1024*512,
      WtAll + (size_t)1536*512, WtAll + (size_t)2048*512, WtO, WtLog);

  // ---- cycle 0 ----
  // Q -> qbuf, K|V -> KeVe (persists; doubles as Kh/Vh since h==e)
  gemm_mfma_bf<<<dim3(12,64), 256, 0, stream>>>(ebf, WtAll,
      sat_qb, sat_kb, sat_vb, sat_vb, sat_vb, qbuf, 512, KeVe, 1024, 512);
  s_proj<<<80, 256, 0, stream>>>(s,
      sat_kw, sat_vw, rel_qw, rel_kw, rel_vw,
      sat_kb, sat_vb, rel_qb, rel_kb, rel_vb,
      KsVs, KsVs + 512, qr, Ksr, Vsr,
      1024, 1024, 512, 512, 512);
  sat_attn<<<MM*NHH/4, 256, 0, stream>>>(qbuf, 512, KeVe, KeVe + 512, 1024,
                                         KeVe, KsVs, ctxbf);
  gemm_mfma_bf<<<dim3(4,64), 256, 0, stream>>>(ctxbf, WtO,
      sat_ob, sat_ob, sat_ob, sat_ob, sat_ob, aout, 512, aout, 512, 512);
  relu_ln_bf<<<MM, 256, 0, stream>>>(aout, ln_sat_w, ln_sat_b, hbf);
  // merged: qkv(c1) [N=1536] + rel K|V(c0) [N=1024] from the same hbf
  gemm_mfma_bf<<<dim3(20,64), 256, 0, stream>>>(hbf, WtAll,
      sat_qb, sat_kb, sat_vb, rel_kb, rel_vb, qkv, 1536, kvbuf, 1024, 1536);
  rel_part<<<dim3(RCH, NHH, BB), 256, 0, stream>>>(qr, Ksr, Vsr, kvbuf, pws);
  rel_tail<<<BB, 256, 0, stream>>>(pws, rel_ow, rel_ob, ln_rel_w, ln_rel_b, s);

  // ---- cycle 1 (rel path dead: s is never consumed after this cycle) ----
  s_proj<<<32, 256, 0, stream>>>(s,
      sat_kw, sat_vw, sat_vw, sat_vw, sat_vw,
      sat_kb, sat_vb, sat_vb, sat_vb, sat_vb,
      KsVs, KsVs + 512, Ksr, Ksr, Ksr,
      1024, 1024, 512, 512, 512);
  sat_attn<<<MM*NHH/4, 256, 0, stream>>>(qkv, 1536, qkv + 512, qkv + 1024, 1536,
                                         KeVe, KsVs, ctxbf);
  gemm_mfma_bf<<<dim3(4,64), 256, 0, stream>>>(ctxbf, WtO,
      sat_ob, sat_ob, sat_ob, sat_ob, sat_ob, aout, 512, aout, 512, 512);
  relu_ln_bf<<<MM, 256, 0, stream>>>(aout, ln_sat_w, ln_sat_b, hbf);

  gemm_logits<<<dim3(1,64), 256, 0, stream>>>(hbf, WtLog, ofc_b, (float*)d_out);
}

// Round 11
// 336.308 us; speedup vs baseline: 1.3426x; 1.1207x over previous
//
#include <hip/hip_runtime.h>
#include <hip/hip_bf16.h>

typedef __hip_bfloat16 bf16;

#define BB 16
#define LL 512
#define DD 512
#define NHH 8
#define HDD 64
#define TT 17
#define MM (BB*LL)   // 8192 rows
#define RCH 8        // rel-attn key chunks
#define RCK 65       // keys per chunk (8*65=520 >= 513)

typedef __attribute__((ext_vector_type(8))) short bfrag;   // 8 bf16
typedef __attribute__((ext_vector_type(4))) float ffrag;   // 4 fp32
typedef __attribute__((ext_vector_type(8))) unsigned short us8;

static __device__ __forceinline__ void gld16(const void* g, void* l){
  __builtin_amdgcn_global_load_lds((const __attribute__((address_space(1))) void*)g,
                                   (__attribute__((address_space(3))) void*)l, 16, 0, 0);
}
static __device__ __forceinline__ float us2f(unsigned short u){
  unsigned int v = ((unsigned int)u) << 16;
  float f; __builtin_memcpy(&f, &v, 4); return f;
}
// sum across the 8-lane group (head) — xor 1,2,4 stays inside the group
static __device__ __forceinline__ float hsum8(float v){
  v += __shfl_xor(v, 1);
  v += __shfl_xor(v, 2);
  v += __shfl_xor(v, 4);
  return v;
}

// ---------------- fused embed gather + mean partial sums ----------------
__global__ __launch_bounds__(256)
void emean(const int* __restrict__ tokens, const float* __restrict__ emb,
           bf16* __restrict__ ebf, float* __restrict__ mpart){
  int blk = blockIdx.x;
  int b = blk >> 4, lc = blk & 15;
  int t = threadIdx.x;
  __shared__ int toks[32];
  if (t < 32) toks[t] = tokens[b*LL + lc*32 + t];
  __syncthreads();
  bf16* eb = ebf + ((size_t)b*LL + lc*32)*DD;
  for (int d = t; d < DD; d += 256){
    float acc = 0.f;
    #pragma unroll 4
    for (int l = 0; l < 32; l++){
      float v = emb[(size_t)toks[l]*DD + d];
      eb[(size_t)l*DD + d] = __float2bfloat16(v);
      acc += v;
    }
    mpart[(size_t)blk*DD + d] = acc;
  }
}
__global__ void mean2(const float* __restrict__ part, float* __restrict__ s){
  int i = blockIdx.x*256 + threadIdx.x;   // 8192
  int b = i >> 9, d = i & 511;
  float acc = 0.f;
  #pragma unroll
  for (int c = 0; c < 16; c++) acc += part[(size_t)(b*16 + c)*DD + d];
  s[i] = acc * (1.0f/LL);
}

// ---------------- weight prep: 6x transpose->bf16 + padded logits W ----------------
__global__ void prep_w(const float* __restrict__ i0, const float* __restrict__ i1,
                       const float* __restrict__ i2, const float* __restrict__ i3,
                       const float* __restrict__ i4, const float* __restrict__ i5,
                       const float* __restrict__ wlog,
                       bf16* __restrict__ o0, bf16* __restrict__ o1,
                       bf16* __restrict__ o2, bf16* __restrict__ o3,
                       bf16* __restrict__ o4, bf16* __restrict__ o5,
                       bf16* __restrict__ olog){
  int z = blockIdx.z;
  int tx = threadIdx.x, ty = threadIdx.y;       // 32 x 8
  if (z == 6){
    int tid = ty*32 + tx;
    int i = ((blockIdx.y*16 + blockIdx.x) << 8) + tid;   // 0..65535
    int row = i >> 9, k = i & 511;
    olog[i] = __float2bfloat16(row < TT ? wlog[(size_t)k*TT + row] : 0.f);
    return;
  }
  __shared__ float tile[32][33];
  const float* in = (z==0)?i0:(z==1)?i1:(z==2)?i2:(z==3)?i3:(z==4)?i4:i5;
  bf16* out       = (z==0)?o0:(z==1)?o1:(z==2)?o2:(z==3)?o3:(z==4)?o4:o5;
  int bx = blockIdx.x*32, by = blockIdx.y*32;
  #pragma unroll
  for (int j = 0; j < 32; j += 8)
    tile[ty + j][tx] = in[(size_t)(by + ty + j)*DD + bx + tx];
  __syncthreads();
  #pragma unroll
  for (int j = 0; j < 32; j += 8)
    out[(size_t)(bx + ty + j)*DD + by + tx] = __float2bfloat16(tile[tx][ty + j]);
}

// ---------------- MFMA GEMM, bf16 output, split destination, XCD-swizzled 1D grid ----------------
// launch with grid = GX*64 (1D); by-band of 8 per XCD so each XCD fetches its A slice once
__global__ __launch_bounds__(256)
void gemm_mfma_bf(const bf16* __restrict__ A, const bf16* __restrict__ Wt,
                  const float* __restrict__ b0, const float* __restrict__ b1,
                  const float* __restrict__ b2, const float* __restrict__ b3,
                  const float* __restrict__ b4,
                  bf16* __restrict__ D0, int ld0,
                  bf16* __restrict__ D1, int ld1, int split){
  const int K = 512;
  __shared__ bf16 As[128*32];
  __shared__ bf16 Bs[128*32];
  int t = threadIdx.x;
  int wave = t >> 6, lane = t & 63;
  int id = blockIdx.x;
  int bm = (((id & 7) << 3) | ((id >> 3) & 7)) * 128;   // by: XCD-clustered
  int bn = (id >> 6) * 128;
  int wm = (wave & 1) * 64, wn = (wave >> 1) * 64;
  ffrag acc[4][4];
  #pragma unroll
  for (int i = 0; i < 4; i++)
    #pragma unroll
    for (int j = 0; j < 4; j++) acc[i][j] = (ffrag){0.f,0.f,0.f,0.f};

  int srow = t >> 2;
  int scol = (t & 3) * 8;
  const bf16* gA = A  + (size_t)(bm + srow)*K + scol;
  const bf16* gB = Wt + (size_t)(bn + srow)*K + scol;
  char* lA = (char*)As + 16*t;
  char* lB = (char*)Bs + 16*t;
  int q = lane >> 4, r = lane & 15;

  for (int k0 = 0; k0 < K; k0 += 32){
    gld16(gA + k0,          lA);
    gld16(gA + 64*K + k0,   lA + 4096);
    gld16(gB + k0,          lB);
    gld16(gB + 64*K + k0,   lB + 4096);
    __syncthreads();
    bfrag af[4], bfv[4];
    #pragma unroll
    for (int i = 0; i < 4; i++){
      af[i]  = *(const bfrag*)(As + (wm + i*16 + r)*32 + q*8);
      bfv[i] = *(const bfrag*)(Bs + (wn + i*16 + r)*32 + q*8);
    }
    #pragma unroll
    for (int i = 0; i < 4; i++)
      #pragma unroll
      for (int j = 0; j < 4; j++)
        acc[i][j] = __builtin_amdgcn_mfma_f32_16x16x32_bf16(af[i], bfv[j], acc[i][j], 0, 0, 0);
    __syncthreads();
  }
  #pragma unroll
  for (int i = 0; i < 4; i++){
    #pragma unroll
    for (int j = 0; j < 4; j++){
      int row = bm + wm + i*16 + q*4;
      int col = bn + wn + j*16 + r;
      const float* bp = (col < 512) ? b0 : (col < 1024) ? b1 :
                        (col < 1536) ? b2 : (col < 2048) ? b3 : b4;
      float bias = bp[col & 511];
      bf16* D; int ld;
      if (col < split){ D = D0 + (size_t)row*ld0 + col;         ld = ld0; }
      else            { D = D1 + (size_t)row*ld1 + (col-split); ld = ld1; }
      #pragma unroll
      for (int g = 0; g < 4; g++)
        D[(size_t)g*ld] = __float2bfloat16(acc[i][j][g] + bias);
    }
  }
}

// ---------------- logits MFMA: only cols<32 computed (17 used) ----------------
__global__ __launch_bounds__(256)
void gemm_logits(const bf16* __restrict__ A, const bf16* __restrict__ Wt,
                 const float* __restrict__ bias, float* __restrict__ C){
  const int K = 512;
  __shared__ bf16 As[128*32];
  __shared__ bf16 Bs[128*32];
  int t = threadIdx.x;
  int wave = t >> 6, lane = t & 63;
  int bm = blockIdx.y * 128;
  int wm = (wave & 1) * 64, wn = (wave >> 1) * 64;
  ffrag acc[2];
  acc[0] = (ffrag){0.f,0.f,0.f,0.f};
  acc[1] = (ffrag){0.f,0.f,0.f,0.f};

  int srow = t >> 2;
  int scol = (t & 3) * 8;
  const bf16* gA = A  + (size_t)(bm + srow)*K + scol;
  const bf16* gB = Wt + (size_t)srow*K + scol;
  char* lA = (char*)As + 16*t;
  char* lB = (char*)Bs + 16*t;
  int q = lane >> 4, r = lane & 15;

  for (int k0 = 0; k0 < K; k0 += 32){
    gld16(gA + k0,          lA);
    gld16(gA + 64*K + k0,   lA + 4096);
    gld16(gB + k0,          lB);
    gld16(gB + 64*K + k0,   lB + 4096);
    __syncthreads();
    if (wn == 0){
      #pragma unroll
      for (int i = 0; i < 4; i++){
        bfrag af = *(const bfrag*)(As + (wm + i*16 + r)*32 + q*8);
        if (i < 2){
          bfrag bfv = *(const bfrag*)(Bs + (i*16 + r)*32 + q*8);
          // note: need af for all i but bf only j<2 — restructure below
        }
      }
      // compute: 4 row-frags x 2 col-frags
      bfrag bf0 = *(const bfrag*)(Bs + (0*16 + r)*32 + q*8);
      bfrag bf1 = *(const bfrag*)(Bs + (1*16 + r)*32 + q*8);
      #pragma unroll
      for (int i = 0; i < 4; i++){
        bfrag af = *(const bfrag*)(As + (wm + i*16 + r)*32 + q*8);
        // accumulate rows into 2 col-frag accumulators per row-frag:
        // store per-(i) results into acc via separate regs
        // we use 8 accumulators total: pack as acc8[i][j]
        // (declared below as static arrays)
        // -- handled by acc8 --
        (void)af; (void)bf0; (void)bf1;
      }
    }
    __syncthreads();
  }
  // NOTE: the masked-MFMA restructure is done in gemm_logits2 below; this body unused.
  (void)acc; (void)bias; (void)C; (void)wn;
}

// clean masked logits kernel: 4 row-frags x 2 col-frags on wave-col 0 only
__global__ __launch_bounds__(256)
void gemm_logits2(const bf16* __restrict__ A, const bf16* __restrict__ Wt,
                  const float* __restrict__ bias, float* __restrict__ C){
  const int K = 512;
  __shared__ bf16 As[128*32];
  __shared__ bf16 Bs[128*32];
  int t = threadIdx.x;
  int wave = t >> 6, lane = t & 63;
  int bm = blockIdx.y * 128;
  int wm = (wave & 1) * 64, wn = (wave >> 1) * 64;
  ffrag acc[4][2];
  #pragma unroll
  for (int i = 0; i < 4; i++){ acc[i][0] = (ffrag){0,0,0,0}; acc[i][1] = (ffrag){0,0,0,0}; }

  int srow = t >> 2;
  int scol = (t & 3) * 8;
  const bf16* gA = A  + (size_t)(bm + srow)*K + scol;
  const bf16* gB = Wt + (size_t)srow*K + scol;
  char* lA = (char*)As + 16*t;
  char* lB = (char*)Bs + 16*t;
  int q = lane >> 4, r = lane & 15;

  for (int k0 = 0; k0 < K; k0 += 32){
    gld16(gA + k0,          lA);
    gld16(gA + 64*K + k0,   lA + 4096);
    gld16(gB + k0,          lB);
    gld16(gB + 64*K + k0,   lB + 4096);
    __syncthreads();
    if (wn == 0){
      bfrag bf0 = *(const bfrag*)(Bs + (r)*32 + q*8);        // cols 0..15
      bfrag bf1 = *(const bfrag*)(Bs + (16 + r)*32 + q*8);   // cols 16..31
      #pragma unroll
      for (int i = 0; i < 4; i++){
        bfrag af = *(const bfrag*)(As + (wm + i*16 + r)*32 + q*8);
        acc[i][0] = __builtin_amdgcn_mfma_f32_16x16x32_bf16(af, bf0, acc[i][0], 0, 0, 0);
        acc[i][1] = __builtin_amdgcn_mfma_f32_16x16x32_bf16(af, bf1, acc[i][1], 0, 0, 0);
      }
    }
    __syncthreads();
  }
  if (wn == 0){
    #pragma unroll
    for (int i = 0; i < 4; i++){
      #pragma unroll
      for (int j = 0; j < 2; j++){
        int row = bm + wm + i*16 + q*4;
        int col = j*16 + r;
        if (col < TT){
          float bias_v = bias[col];
          #pragma unroll
          for (int g = 0; g < 4; g++)
            C[(size_t)(row + g)*TT + col] = acc[i][j][g] + bias_v;
        }
      }
    }
  }
}

// ---------------- batched s-projections: 8-way split-k, 32-col chunks (fp32) ----------------
__global__ __launch_bounds__(256)
void s_proj(const float* __restrict__ A,
            const float* __restrict__ W0, const float* __restrict__ W1,
            const float* __restrict__ W2, const float* __restrict__ W3,
            const float* __restrict__ W4,
            const float* __restrict__ bias0, const float* __restrict__ bias1,
            const float* __restrict__ bias2, const float* __restrict__ bias3,
            const float* __restrict__ bias4,
            float* __restrict__ O0, float* __restrict__ O1,
            float* __restrict__ O2, float* __restrict__ O3,
            float* __restrict__ O4,
            int ldc0, int ldc1, int ldc2, int ldc3, int ldc4){
  __shared__ float part[8][32][17];
  int t = threadIdx.x;
  int n = t & 31, kg = t >> 5;
  int wi = blockIdx.x >> 4, ch = blockIdx.x & 15;
  const float* W  = (wi==0)?W0:(wi==1)?W1:(wi==2)?W2:(wi==3)?W3:W4;
  const float* bs = (wi==0)?bias0:(wi==1)?bias1:(wi==2)?bias2:(wi==3)?bias3:bias4;
  float* O  = (wi==0)?O0:(wi==1)?O1:(wi==2)?O2:(wi==3)?O3:O4;
  int ldc   = (wi==0)?ldc0:(wi==1)?ldc1:(wi==2)?ldc2:(wi==3)?ldc3:ldc4;
  int col = ch*32 + n;
  float acc[16];
  #pragma unroll
  for (int m = 0; m < 16; m++) acc[m] = 0.f;
  const float* Wp = W + (size_t)(kg*64)*512 + col;
  const float* Ap = A + kg*64;
  for (int k = 0; k < 64; k++){
    float w = Wp[(size_t)k*512];
    #pragma unroll
    for (int m = 0; m < 16; m++) acc[m] = fmaf(Ap[m*512 + k], w, acc[m]);
  }
  #pragma unroll
  for (int m = 0; m < 16; m++) part[kg][n][m] = acc[m];
  __syncthreads();
  for (int o = t; o < 512; o += 256){
    int m = o >> 5, nn = o & 31;
    float v = 0.f;
    #pragma unroll
    for (int g = 0; g < 8; g++) v += part[g][nn][m];
    O[(size_t)m*ldc + ch*32 + nn] = v + bs[ch*32 + nn];
  }
}

// ---------------- sat attention: one wave per token, us8 loads, 8-lane heads ----------------
__global__ __launch_bounds__(256)
void sat_attn(const bf16* __restrict__ qp, int sq,
              const bf16* __restrict__ kp, const bf16* __restrict__ vp, int skv,
              const bf16* __restrict__ KeVe, const float* __restrict__ KsVs,
              bf16* __restrict__ ctx){
  int tok = blockIdx.x*4 + (threadIdx.x >> 6);
  int l = threadIdx.x & 63;                 // lane: dims l*8..l*8+7; head = l>>3
  int b = tok >> 9, li = tok & 511;
  int off = l*8;
  int t0 = (b << 9) | ((li + 1) & 511);
  int t2 = (b << 9) | (li == 0 ? 511 : 0);

  float qf[8];
  { us8 q8 = *(const us8*)(qp + (size_t)tok*sq + off);
    #pragma unroll
    for (int g = 0; g < 8; g++) qf[g] = us2f(q8[g]); }

  float sc[5];
  // key 0..2: h rows t0, tok, t2
  int rows[3] = {t0, tok, t2};
  #pragma unroll
  for (int j = 0; j < 3; j++){
    us8 k8 = *(const us8*)(kp + (size_t)rows[j]*skv + off);
    float a = 0.f;
    #pragma unroll
    for (int g = 0; g < 8; g++) a += qf[g]*us2f(k8[g]);
    sc[j] = hsum8(a) * 0.125f;
  }
  { us8 k8 = *(const us8*)(KeVe + (size_t)tok*1024 + off);
    float a = 0.f;
    #pragma unroll
    for (int g = 0; g < 8; g++) a += qf[g]*us2f(k8[g]);
    sc[3] = hsum8(a) * 0.125f; }
  { const float* ks = KsVs + (size_t)b*1024 + off;
    float4 f0 = *(const float4*)ks, f1 = *(const float4*)(ks + 4);
    float a = qf[0]*f0.x + qf[1]*f0.y + qf[2]*f0.z + qf[3]*f0.w
            + qf[4]*f1.x + qf[5]*f1.y + qf[6]*f1.z + qf[7]*f1.w;
    sc[4] = hsum8(a) * 0.125f; }

  float m = fmaxf(fmaxf(fmaxf(sc[0],sc[1]), fmaxf(sc[2],sc[3])), sc[4]);
  float p[5], den = 0.f;
  #pragma unroll
  for (int j = 0; j < 5; j++){ p[j] = __expf(sc[j]-m); den += p[j]; }
  float inv = 1.0f/den;

  float o[8];
  #pragma unroll
  for (int g = 0; g < 8; g++) o[g] = 0.f;
  #pragma unroll
  for (int j = 0; j < 3; j++){
    us8 v8 = *(const us8*)(vp + (size_t)rows[j]*skv + off);
    #pragma unroll
    for (int g = 0; g < 8; g++) o[g] += p[j]*us2f(v8[g]);
  }
  { us8 v8 = *(const us8*)(KeVe + (size_t)tok*1024 + 512 + off);
    #pragma unroll
    for (int g = 0; g < 8; g++) o[g] += p[3]*us2f(v8[g]); }
  { const float* vs = KsVs + (size_t)b*1024 + 512 + off;
    float4 f0 = *(const float4*)vs, f1 = *(const float4*)(vs + 4);
    o[0] += p[4]*f0.x; o[1] += p[4]*f0.y; o[2] += p[4]*f0.z; o[3] += p[4]*f0.w;
    o[4] += p[4]*f1.x; o[5] += p[4]*f1.y; o[6] += p[4]*f1.z; o[7] += p[4]*f1.w; }

  bf16 ob[8];
  #pragma unroll
  for (int g = 0; g < 8; g++) ob[g] = __float2bfloat16(o[g]*inv);
  *(us8*)(ctx + (size_t)tok*DD + off) = *(const us8*)ob;
}

// ---------------- rel attention pass 1 (bf16 KV, fp32 s-row) ----------------
__global__ __launch_bounds__(256)
void rel_part(const float* __restrict__ q, const float* __restrict__ Ksr,
              const float* __restrict__ Vsr, const bf16* __restrict__ KV,
              float* __restrict__ pws){
  int ch = blockIdx.x, hh = blockIdx.y, b = blockIdx.z;
  int t = threadIdx.x;
  int base = hh * HDD;
  __shared__ __align__(16) float qs[64];
  __shared__ float sc[RCK];
  __shared__ float red[256];
  __shared__ float part[4][64];
  int j0 = ch * RCK;
  int nk = min(513 - j0, RCK);
  if (t < 64) qs[t] = q[(size_t)b*DD + base + t];
  __syncthreads();
  if (t < nk){
    int j = j0 + t;
    float a = 0.f;
    if (j == 0){
      const float* kr = Ksr + (size_t)b*DD + base;
      #pragma unroll
      for (int d = 0; d < 64; d += 4){
        float4 k4 = *(const float4*)(kr + d);
        float4 q4 = *(const float4*)(qs + d);
        a += q4.x*k4.x + q4.y*k4.y + q4.z*k4.z + q4.w*k4.w;
      }
    } else {
      const bf16* kr = KV + ((size_t)b*LL + j - 1)*1024 + base;
      #pragma unroll
      for (int d = 0; d < 64; d += 8){
        us8 k8 = *(const us8*)(kr + d);
        #pragma unroll
        for (int g = 0; g < 8; g++) a += qs[d+g] * us2f(k8[g]);
      }
    }
    sc[t] = a * 0.125f;
  }
  __syncthreads();
  red[t] = (t < nk) ? sc[t] : -1e30f; __syncthreads();
  for (int st = 128; st; st >>= 1){ if (t < st) red[t] = fmaxf(red[t], red[t+st]); __syncthreads(); }
  float m = red[0]; __syncthreads();
  if (t < nk) sc[t] = __expf(sc[t] - m);
  __syncthreads();
  red[t] = (t < nk) ? sc[t] : 0.f; __syncthreads();
  for (int st = 128; st; st >>= 1){ if (t < st) red[t] += red[t+st]; __syncthreads(); }
  float l = red[0];
  int d = t & 63, c2 = t >> 6;
  float a = 0.f;
  for (int j = c2; j < nk; j += 4){
    int gj = j0 + j;
    float vv = (gj == 0) ? Vsr[(size_t)b*DD + base + d]
                         : __bfloat162float(KV[((size_t)b*LL + gj - 1)*1024 + 512 + base + d]);
    a += sc[j] * vv;
  }
  part[c2][d] = a; __syncthreads();
  float* o = pws + (((size_t)(b*NHH + hh))*RCH + ch) * 66;
  if (t < 64) o[t] = part[0][t] + part[1][t] + part[2][t] + part[3][t];
  else if (t == 64) o[64] = m;
  else if (t == 65) o[65] = l;
}

// ---------------- fused rel tail: combine chunks -> out-proj -> relu+LN -> s ----------------
__global__ __launch_bounds__(256)
void rel_tail(const float* __restrict__ pws, const float* __restrict__ W,
              const float* __restrict__ bias, const float* __restrict__ lnw,
              const float* __restrict__ lnb, float* __restrict__ s){
  int b = blockIdx.x;
  int t = threadIdx.x;
  __shared__ float crs[512];
  __shared__ float red[256];
  for (int o = t; o < 512; o += 256){
    int hh = o >> 6, d = o & 63;
    const float* p = pws + ((size_t)(b*NHH + hh))*RCH*66;
    float M = -1e30f;
    #pragma unroll
    for (int c = 0; c < RCH; c++) M = fmaxf(M, p[c*66 + 64]);
    float den = 0.f, acc = 0.f;
    #pragma unroll
    for (int c = 0; c < RCH; c++){
      float w = __expf(p[c*66 + 64] - M);
      den += w * p[c*66 + 65];
      acc += w * p[c*66 + d];
    }
    crs[o] = acc / den;
  }
  __syncthreads();
  int n0 = t, n1 = t + 256;
  float a0 = 0.f, a1 = 0.f;
  for (int k = 0; k < 512; k++){
    float c = crs[k];
    a0 = fmaf(c, W[(size_t)k*512 + n0], a0);
    a1 = fmaf(c, W[(size_t)k*512 + n1], a1);
  }
  a0 += bias[n0]; a1 += bias[n1];
  float v0 = fmaxf(a0, 0.f), v1 = fmaxf(a1, 0.f);
  red[t] = v0 + v1; __syncthreads();
  for (int st = 128; st; st >>= 1){ if (t < st) red[t] += red[t+st]; __syncthreads(); }
  float u = red[0] * (1.0f/DD); __syncthreads();
  float d0 = v0 - u, d1 = v1 - u;
  red[t] = d0*d0 + d1*d1; __syncthreads();
  for (int st = 128; st; st >>= 1){ if (t < st) red[t] += red[t+st]; __syncthreads(); }
  float inv = rsqrtf(red[0] * (1.0f/DD) + 1e-12f);
  // s MUST be written — it feeds the next cycle (round-5 lesson).
  s[(size_t)b*DD + n0] = lnw[n0]*d0*inv + lnb[n0];
  s[(size_t)b*DD + n1] = lnw[n1]*d1*inv + lnb[n1];
}

// ---------------- h path: y = ln(relu(x)), bf16 in -> bf16 out ----------------
__global__ void relu_ln_bf(const bf16* __restrict__ X, const float* __restrict__ w,
                           const float* __restrict__ bn, bf16* __restrict__ Ybf){
  int row = blockIdx.x;
  int tid = threadIdx.x; // 256
  __shared__ float red[256];
  const bf16* x = X + (size_t)row*DD;
  float v0 = fmaxf(__bfloat162float(x[tid]), 0.f);
  float v1 = fmaxf(__bfloat162float(x[tid+256]), 0.f);
  red[tid] = v0 + v1;
  __syncthreads();
  for (int st = 128; st; st >>= 1){ if (tid < st) red[tid] += red[tid+st]; __syncthreads(); }
  float u = red[0] * (1.0f/DD);
  __syncthreads();
  float d0 = v0 - u, d1 = v1 - u;
  red[tid] = d0*d0 + d1*d1;
  __syncthreads();
  for (int st = 128; st; st >>= 1){ if (tid < st) red[tid] += red[tid+st]; __syncthreads(); }
  float var = red[0] * (1.0f/DD);
  float inv = rsqrtf(var + 1e-12f);
  Ybf[(size_t)row*DD + tid]       = __float2bfloat16(w[tid]    *d0*inv + bn[tid]);
  Ybf[(size_t)row*DD + tid + 256] = __float2bfloat16(w[tid+256]*d1*inv + bn[tid+256]);
}

extern "C" void kernel_launch(void* const* d_in, const int* in_sizes, int n_in,
                              void* d_out, int out_size, void* d_ws, size_t ws_size,
                              hipStream_t stream) {
  const int*   tokens  = (const int*)  d_in[0];
  const float* emb     = (const float*)d_in[4];
  const float* sat_qw  = (const float*)d_in[5];
  const float* sat_qb  = (const float*)d_in[6];
  const float* sat_kw  = (const float*)d_in[7];
  const float* sat_kb  = (const float*)d_in[8];
  const float* sat_vw  = (const float*)d_in[9];
  const float* sat_vb  = (const float*)d_in[10];
  const float* sat_ow  = (const float*)d_in[11];
  const float* sat_ob  = (const float*)d_in[12];
  const float* rel_qw  = (const float*)d_in[13];
  const float* rel_qb  = (const float*)d_in[14];
  const float* rel_kw  = (const float*)d_in[15];
  const float* rel_kb  = (const float*)d_in[16];
  const float* rel_vw  = (const float*)d_in[17];
  const float* rel_vb  = (const float*)d_in[18];
  const float* rel_ow  = (const float*)d_in[19];
  const float* rel_ob  = (const float*)d_in[20];
  const float* ln_sat_w= (const float*)d_in[21];
  const float* ln_sat_b= (const float*)d_in[22];
  const float* ln_rel_w= (const float*)d_in[23];
  const float* ln_rel_b= (const float*)d_in[24];
  const float* ofc_w   = (const float*)d_in[25];
  const float* ofc_b   = (const float*)d_in[26];

  char* p = (char*)d_ws;
  auto alloc = [&](size_t bytes) -> char* {
    char* r = p; p += (bytes + 255) & ~(size_t)255; return r;
  };
  const size_t BIGH = (size_t)MM*DD*2;          // 8 MB (bf16 M x 512)
  bf16*  ebf   = (bf16*) alloc(BIGH);           // e bf16; later reused as hbf
  bf16*  qkv   = (bf16*) alloc(3*BIGH);         // [M,1536] bf16; aliased: aout
  bf16*  kvbuf = (bf16*) alloc(2*BIGH);         // [M,1024] rel K|V (cycle 0)
  bf16*  KeVe  = (bf16*) alloc(2*BIGH);         // [M,1024] bf16 (persists)
  bf16*  qbuf  = (bf16*) alloc(BIGH);           // cycle-0 Q [M,512]
  bf16*  ctxbf = (bf16*) alloc(BIGH);
  bf16*  WtAll = (bf16*) alloc((size_t)2560*512*2);  // sat_q|sat_k|sat_v|rel_k|rel_v ^T
  bf16*  WtO   = (bf16*) alloc((size_t)512*512*2);
  bf16*  WtLog = (bf16*) alloc((size_t)128*512*2);
  float* s     = (float*)alloc(BB*DD*4);
  float* KsVs  = (float*)alloc(BB*1024*4);
  float* qr    = (float*)alloc(BB*DD*4);
  float* Ksr   = (float*)alloc(BB*DD*4);
  float* Vsr   = (float*)alloc(BB*DD*4);
  float* mpart = (float*)alloc((size_t)256*DD*4);          // mean partials
  float* pws   = (float*)alloc((size_t)BB*NHH*RCH*66*4);   // rel partials
  bf16*  hbf   = ebf;                           // reuse: e_bf dead after cycle-0 Q/KeVe/mean
  bf16*  aout  = qkv;                           // reuse: qkv region between uses

  emean<<<256, 256, 0, stream>>>(tokens, emb, ebf, mpart);
  mean2<<<32, 256, 0, stream>>>(mpart, s);

  prep_w<<<dim3(16,16,7), dim3(32,8), 0, stream>>>(
      sat_qw, sat_kw, sat_vw, rel_kw, rel_vw, sat_ow, ofc_w,
      WtAll, WtAll + (size_t)512*512, WtAll + (size_t)1024*512,
      WtAll + (size_t)1536*512, WtAll + (size_t)2048*512, WtO, WtLog);

  // ---- cycle 0 ----
  gemm_mfma_bf<<<12*64, 256, 0, stream>>>(ebf, WtAll,
      sat_qb, sat_kb, sat_vb, sat_vb, sat_vb, qbuf, 512, KeVe, 1024, 512);
  s_proj<<<80, 256, 0, stream>>>(s,
      sat_kw, sat_vw, rel_qw, rel_kw, rel_vw,
      sat_kb, sat_vb, rel_qb, rel_kb, rel_vb,
      KsVs, KsVs + 512, qr, Ksr, Vsr,
      1024, 1024, 512, 512, 512);
  sat_attn<<<MM/4, 256, 0, stream>>>(qbuf, 512, KeVe, KeVe + 512, 1024,
                                     KeVe, KsVs, ctxbf);
  gemm_mfma_bf<<<4*64, 256, 0, stream>>>(ctxbf, WtO,
      sat_ob, sat_ob, sat_ob, sat_ob, sat_ob, aout, 512, aout, 512, 512);
  relu_ln_bf<<<MM, 256, 0, stream>>>(aout, ln_sat_w, ln_sat_b, hbf);
  // merged: qkv(c1) [N=1536] + rel K|V(c0) [N=1024] from the same hbf
  gemm_mfma_bf<<<20*64, 256, 0, stream>>>(hbf, WtAll,
      sat_qb, sat_kb, sat_vb, rel_kb, rel_vb, qkv, 1536, kvbuf, 1024, 1536);
  rel_part<<<dim3(RCH, NHH, BB), 256, 0, stream>>>(qr, Ksr, Vsr, kvbuf, pws);
  rel_tail<<<BB, 256, 0, stream>>>(pws, rel_ow, rel_ob, ln_rel_w, ln_rel_b, s);

  // ---- cycle 1 (rel path dead: s is never consumed after this cycle) ----
  s_proj<<<32, 256, 0, stream>>>(s,
      sat_kw, sat_vw, sat_vw, sat_vw, sat_vw,
      sat_kb, sat_vb, sat_vb, sat_vb, sat_vb,
      KsVs, KsVs + 512, Ksr, Ksr, Ksr,
      1024, 1024, 512, 512, 512);
  sat_attn<<<MM/4, 256, 0, stream>>>(qkv, 1536, qkv + 512, qkv + 1024, 1536,
                                     KeVe, KsVs, ctxbf);
  gemm_mfma_bf<<<4*64, 256, 0, stream>>>(ctxbf, WtO,
      sat_ob, sat_ob, sat_ob, sat_ob, sat_ob, aout, 512, aout, 512, 512);
  relu_ln_bf<<<MM, 256, 0, stream>>>(aout, ln_sat_w, ln_sat_b, hbf);

  gemm_logits2<<<dim3(1,64), 256, 0, stream>>>(hbf, WtLog, ofc_b, (float*)d_out);
}